// Round 10
// baseline (156.601 us; speedup 1.0000x reference)
//
#include <hip/hip_runtime.h>
#include <cstdint>
#include <cstddef>

#define NROWS 4096
#define DIM   1024            // elements per row; also BYTES per fp8 row
#define TWON  8192
#define INV_T 2.0f
// exp(2.0) = exp(sim_rr / T) for the masked diagonal (rows are unit-norm)
#define EXP_DIAG 7.38905609893065f
#define NT2   1056            // # of 256x128 tiles covering the upper triangle
#define SCALE1 0x7F7F7F7F     // 4x E8M0 unity scales (127 -> 2^0)

typedef float floatx4 __attribute__((ext_vector_type(4)));
typedef int   intx4   __attribute__((ext_vector_type(4)));
typedef int   intx8   __attribute__((ext_vector_type(8)));

union F8 { intx8 v8; intx4 v4[2]; };

__device__ __forceinline__ void gload16(const uint8_t* g, uint8_t* l) {
  __builtin_amdgcn_global_load_lds(
      (const __attribute__((address_space(1))) void*)g,
      (__attribute__((address_space(3))) void*)l,
      16, 0, 0);
}

// -- kernel 1: normalize -> fp8 reps, fp32 pos dot, zero denom/cnt ------------
// Wave-per-pair, no barriers, loads issued up front, HW packed fp8 convert.
__global__ __launch_bounds__(256) void normpos_kernel(
    const float* __restrict__ emb_i, const float* __restrict__ emb_j,
    uint8_t* __restrict__ reps, float* __restrict__ denom,
    float* __restrict__ pos, unsigned int* __restrict__ cnt) {
  const int t    = threadIdx.x;
  const int lane = t & 63;
  const int wave = t >> 6;
  if (blockIdx.x < 32) denom[blockIdx.x * 256 + t] = 0.f;
  if (blockIdx.x == 32 && t == 0) *cnt = 0u;

  const int k = blockIdx.x * 4 + wave;        // 0..4095 (pair index)
  const float4* pi = reinterpret_cast<const float4*>(emb_i + (size_t)k * DIM);
  const float4* pj = reinterpret_cast<const float4*>(emb_j + (size_t)k * DIM);

  float4 vi[4], vj[4];
#pragma unroll
  for (int q = 0; q < 4; ++q) vi[q] = pi[lane + 64 * q];
#pragma unroll
  for (int q = 0; q < 4; ++q) vj[q] = pj[lane + 64 * q];

  float ssi = 0.f, ssj = 0.f, dot = 0.f;
#pragma unroll
  for (int q = 0; q < 4; ++q) {
    ssi += vi[q].x * vi[q].x + vi[q].y * vi[q].y + vi[q].z * vi[q].z + vi[q].w * vi[q].w;
    ssj += vj[q].x * vj[q].x + vj[q].y * vj[q].y + vj[q].z * vj[q].z + vj[q].w * vj[q].w;
    dot += vi[q].x * vj[q].x + vi[q].y * vj[q].y + vi[q].z * vj[q].z + vi[q].w * vj[q].w;
  }
#pragma unroll
  for (int o = 32; o; o >>= 1) {
    ssi += __shfl_xor(ssi, o, 64);
    ssj += __shfl_xor(ssj, o, 64);
    dot += __shfl_xor(dot, o, 64);
  }
  const float invi = 1.0f / fmaxf(sqrtf(ssi), 1e-12f);
  const float invj = 1.0f / fmaxf(sqrtf(ssj), 1e-12f);

  uint32_t* poi = reinterpret_cast<uint32_t*>(reps + (size_t)k * DIM);
  uint32_t* poj = reinterpret_cast<uint32_t*>(reps + (size_t)(k + NROWS) * DIM);
#pragma unroll
  for (int q = 0; q < 4; ++q) {
    int di = __builtin_amdgcn_cvt_pk_fp8_f32(vi[q].x * invi, vi[q].y * invi, 0, false);
    di     = __builtin_amdgcn_cvt_pk_fp8_f32(vi[q].z * invi, vi[q].w * invi, di, true);
    int dj = __builtin_amdgcn_cvt_pk_fp8_f32(vj[q].x * invj, vj[q].y * invj, 0, false);
    dj     = __builtin_amdgcn_cvt_pk_fp8_f32(vj[q].z * invj, vj[q].w * invj, dj, true);
    poi[lane + 64 * q] = (uint32_t)di;
    poj[lane + 64 * q] = (uint32_t)dj;
  }
  if (lane == 0) pos[k] = dot * invi * invj;   // positive-pair cosine, fp32
}

// ---- kernel 2: fused sim-GEMM (MX-fp8) + exp + row/col sums, upper tri -----
// C-tile 256x128, 512 threads = 8 waves (4x2), each wave 4x4 grid of
// 16x16x128 scaled MFMAs, BK=128, DOUBLE-BUFFERED LDS with the
// prefetch-AFTER-barrier K-loop:
//   stage(buf0); for it: { barrier; stage(buf[it+1]); compute(buf[it]); }
// The compiler's vmcnt(0)-before-s_barrier then drains loads issued one full
// compute phase earlier (~free), instead of loads issued immediately before
// (R6-R9 structure: fully exposed latency each iteration). WAR on buffers is
// barrier-protected: prefetch it+1 overwrites buf[it-1] whose readers
// finished before this barrier. LDS 96 KB -> 1 block/CU; within-block
// load/compute overlap replaces cross-block occupancy.
// Verified (R6/R7): A-frag A[m=lane&15][k=quad*32+j]; 32B-slot XOR swizzle
// (key=row&3) conflict-free; C/D col=lane&15,row=quad*4+reg.
__global__ __launch_bounds__(512, 4) void simsum_kernel(
    const uint8_t* __restrict__ reps, float* __restrict__ denom,
    const float* __restrict__ pos, unsigned int* __restrict__ cnt,
    float* __restrict__ out) {
  __shared__ __align__(16) uint8_t lA[2][256 * 128];  // 64 KB
  __shared__ __align__(16) uint8_t lB[2][128 * 128];  // 32 KB
  __shared__ float dl[256];   // row-side partial sums
  __shared__ float cl[128];   // col-side partial sums
  __shared__ unsigned int is_last;

  const int t    = threadIdx.x;
  const int lane = t & 63;
  const int wave = t >> 6;         // 0..7
  const int wm   = wave >> 1;      // wave row 0..3 (64-row strip)
  const int wn   = wave & 1;       // wave col 0..1 (64-col strip)

  // XCD-contiguous tile id, then unrank: f(bm) = bm*(65-bm) tiles before bm
  const int ridx = ((blockIdx.x & 7) * 132) + (blockIdx.x >> 3);  // 0..1055
  int bm = (int)(32.5f - sqrtf(1056.25f - (float)ridx));
  if (bm < 0) bm = 0;
  if (bm > 31) bm = 31;
  while (bm < 31 && (bm + 1) * (65 - (bm + 1)) <= ridx) ++bm;
  while (bm > 0 && bm * (65 - bm) > ridx) --bm;
  const int bn = 2 * bm + (ridx - bm * (65 - bm));   // 2bm..63

  const uint8_t* gA = reps + (size_t)bm * 256 * DIM;
  const uint8_t* gB = reps + (size_t)bn * 128 * DIM;

  // staging: thread t -> row q*64 + rr (rr=t>>3), 16B half-slot s16=t&7.
  // 32B chunk c32 = (s16>>1)^(rr&3); src byte = c32*32 + (s16&1)*16.
  const int rr  = t >> 3;                                      // 0..63
  const int swz = ((((t >> 1) & 3) ^ (rr & 3)) << 5) | ((t & 1) << 4);

  floatx4 acc[4][4];
#pragma unroll
  for (int i = 0; i < 4; ++i)
#pragma unroll
    for (int j = 0; j < 4; ++j) acc[i][j] = floatx4{0.f, 0.f, 0.f, 0.f};

  const int mrow = lane & 15;        // fragment row select
  const int quad = lane >> 4;        // k block 0..3 (32 bytes each)
  const int soff = (quad ^ (mrow & 3)) << 5;   // 32B slot of this lane's chunk

  // prologue: stage k-chunk 0 into buffer 0
#pragma unroll
  for (int q = 0; q < 4; ++q)
    gload16(gA + (size_t)(q * 64 + rr) * DIM + swz, &lA[0][q * 8192 + t * 16]);
#pragma unroll
  for (int q = 0; q < 2; ++q)
    gload16(gB + (size_t)(q * 64 + rr) * DIM + swz, &lB[0][q * 8192 + t * 16]);

#pragma unroll 1
  for (int it = 0; it < 8; ++it) {
    __syncthreads();   // drains buf[it&1] loads (issued one compute phase ago)

    if (it < 7) {      // prefetch next chunk into the other buffer
      const int k0 = (it + 1) * 128;
      const int nb = (it + 1) & 1;
#pragma unroll
      for (int q = 0; q < 4; ++q)
        gload16(gA + (size_t)(q * 64 + rr) * DIM + k0 + swz, &lA[nb][q * 8192 + t * 16]);
#pragma unroll
      for (int q = 0; q < 2; ++q)
        gload16(gB + (size_t)(q * 64 + rr) * DIM + k0 + swz, &lB[nb][q * 8192 + t * 16]);
    }

    const uint8_t* bufA = lA[it & 1];
    const uint8_t* bufB = lB[it & 1];
    F8 fb[4];
#pragma unroll
    for (int nt = 0; nt < 4; ++nt) {
      const uint8_t* p = bufA; (void)p;
      const uint8_t* pb = bufB + (wn * 64 + nt * 16 + mrow) * 128 + soff;
      fb[nt].v4[0] = *reinterpret_cast<const intx4*>(pb);
      fb[nt].v4[1] = *reinterpret_cast<const intx4*>(pb + 16);
    }
#pragma unroll
    for (int mt = 0; mt < 4; ++mt) {
      F8 fa;
      const uint8_t* pa = bufA + (wm * 64 + mt * 16 + mrow) * 128 + soff;
      fa.v4[0] = *reinterpret_cast<const intx4*>(pa);
      fa.v4[1] = *reinterpret_cast<const intx4*>(pa + 16);
#pragma unroll
      for (int nt = 0; nt < 4; ++nt)
        acc[mt][nt] = __builtin_amdgcn_mfma_scale_f32_16x16x128_f8f6f4(
            fa.v8, fb[nt].v8, acc[mt][nt], 0, 0, 0, SCALE1, 0, SCALE1);
    }
  }

  if (t < 256) dl[t] = 0.f;
  else if (t < 384) cl[t - 256] = 0.f;
  __syncthreads();

  // half-tile masks (wave-uniform): h = which 128-row half this wave is in
  const int  h       = wm >> 1;
  const int  r128    = 2 * bm + h;
  const bool skipAll = (r128 > bn);    // below-diagonal half (bn==2bm, h==1)
  const bool doCol   = (r128 < bn);    // strictly-above-diagonal half

  // exp in-place: acc now holds e = exp(sim/T)
#pragma unroll
  for (int mt = 0; mt < 4; ++mt)
#pragma unroll
    for (int nt = 0; nt < 4; ++nt)
#pragma unroll
      for (int r = 0; r < 4; ++r)
        acc[mt][nt][r] = __expf(acc[mt][nt][r] * INV_T);

  // row-sums: C/D layout (16x16): col=lane&15, row=quad*4+r
  if (!skipAll) {
#pragma unroll
    for (int mt = 0; mt < 4; ++mt) {
#pragma unroll
      for (int r = 0; r < 4; ++r) {
        float s = acc[mt][0][r] + acc[mt][1][r] + acc[mt][2][r] + acc[mt][3][r];
        s += __shfl_xor(s, 1, 64);
        s += __shfl_xor(s, 2, 64);
        s += __shfl_xor(s, 4, 64);
        s += __shfl_xor(s, 8, 64);
        if ((lane & 15) == 0)
          atomicAdd(&dl[wm * 64 + mt * 16 + quad * 4 + r], s);
      }
    }
  }

  // col-sums (mirror rows), strictly-off-diagonal halves only
  if (doCol) {
#pragma unroll
    for (int nt = 0; nt < 4; ++nt) {
      float c = 0.f;
#pragma unroll
      for (int mt = 0; mt < 4; ++mt)
#pragma unroll
        for (int r = 0; r < 4; ++r) c += acc[mt][nt][r];
      c += __shfl_xor(c, 16, 64);
      c += __shfl_xor(c, 32, 64);
      if (quad == 0)
        atomicAdd(&cl[wn * 64 + nt * 16 + mrow], c);
    }
  }
  __syncthreads();
  if (t < 256) {
    const bool rowOk = !((bn == 2 * bm) && (t >= 128));
    if (rowOk) atomicAdd(&denom[bm * 256 + t], dl[t]);
  } else if (t < 384 && bn > 2 * bm) {
    atomicAdd(&denom[bn * 128 + (t - 256)], cl[t - 256]);
  }
  // __syncthreads drains vmcnt(0): this block's device-scope denom atomics
  // are complete at the coherence point before the counter bump below.
  __syncthreads();
  if (t == 0)
    is_last = (__hip_atomic_fetch_add(cnt, 1u, __ATOMIC_RELAXED,
                                      __HIP_MEMORY_SCOPE_AGENT) == NT2 - 1)
                  ? 1u : 0u;
  __syncthreads();
  if (is_last) {
    float v = 0.f;
#pragma unroll
    for (int i = 0; i < TWON / 512; ++i) {
      float d = __hip_atomic_load(&denom[i * 512 + t], __ATOMIC_RELAXED,
                                  __HIP_MEMORY_SCOPE_AGENT);
      v += __logf(d - EXP_DIAG);
    }
    float p = 0.f;
#pragma unroll
    for (int i = 0; i < NROWS / 512; ++i)
      p += pos[i * 512 + t];
    v -= 4.0f * p;
#pragma unroll
    for (int o = 32; o; o >>= 1) v += __shfl_down(v, o, 64);
    if ((t & 63) == 0) dl[t >> 6] = v;
    __syncthreads();
    if (t == 0) {
      float tot = 0.f;
#pragma unroll
      for (int w = 0; w < 8; ++w) tot += dl[w];
      out[0] = tot * (1.0f / 8192.0f);
    }
  }
}

extern "C" void kernel_launch(void* const* d_in, const int* in_sizes, int n_in,
                              void* d_out, int out_size, void* d_ws, size_t ws_size,
                              hipStream_t stream) {
  const float* emb_i = (const float*)d_in[0];
  const float* emb_j = (const float*)d_in[1];
  float* out = (float*)d_out;

  uint8_t* reps = (uint8_t*)d_ws;                                  // 8.39 MB fp8
  float* denom  = (float*)((char*)d_ws + (size_t)TWON * DIM);      // 32 KB
  float* pos    = denom + TWON;                                    // 16 KB
  unsigned int* cnt = (unsigned int*)(pos + NROWS);

  normpos_kernel<<<1024, 256, 0, stream>>>(emb_i, emb_j, reps, denom, pos, cnt);
  simsum_kernel<<<NT2, 512, 0, stream>>>(reps, denom, pos, cnt, out);
}

// Round 11
// 151.135 us; speedup vs baseline: 1.0362x; 1.0362x over previous
//
#include <hip/hip_runtime.h>
#include <cstdint>
#include <cstddef>

#define NROWS 4096
#define DIM   1024            // elements per row; also BYTES per fp8 row
#define TWON  8192
#define INV_T 2.0f
// exp(2.0) = exp(sim_rr / T) for the masked diagonal (rows are unit-norm)
#define EXP_DIAG 7.38905609893065f
#define NTILES (64 * 65 / 2)  // 2080 128x128 tiles, upper triangle
#define SCALE1 0x7F7F7F7F     // 4x E8M0 unity scales (127 -> 2^0)

typedef float floatx4 __attribute__((ext_vector_type(4)));
typedef int   intx4   __attribute__((ext_vector_type(4)));
typedef int   intx8   __attribute__((ext_vector_type(8)));

union F8 { intx8 v8; intx4 v4[2]; };

__device__ __forceinline__ void gload16(const uint8_t* g, uint8_t* l) {
  __builtin_amdgcn_global_load_lds(
      (const __attribute__((address_space(1))) void*)g,
      (__attribute__((address_space(3))) void*)l,
      16, 0, 0);
}

// -- kernel 1: normalize -> fp8 reps, fp32 pos dot, zero denom/cnt ------------
// Wave-per-pair, no barriers, loads issued up front, HW packed fp8 convert.
__global__ __launch_bounds__(256) void normpos_kernel(
    const float* __restrict__ emb_i, const float* __restrict__ emb_j,
    uint8_t* __restrict__ reps, float* __restrict__ denom,
    float* __restrict__ pos, unsigned int* __restrict__ cnt) {
  const int t    = threadIdx.x;
  const int lane = t & 63;
  const int wave = t >> 6;
  if (blockIdx.x < 32) denom[blockIdx.x * 256 + t] = 0.f;
  if (blockIdx.x == 32 && t == 0) *cnt = 0u;

  const int k = blockIdx.x * 4 + wave;        // 0..4095 (pair index)
  const float4* pi = reinterpret_cast<const float4*>(emb_i + (size_t)k * DIM);
  const float4* pj = reinterpret_cast<const float4*>(emb_j + (size_t)k * DIM);

  float4 vi[4], vj[4];
#pragma unroll
  for (int q = 0; q < 4; ++q) vi[q] = pi[lane + 64 * q];
#pragma unroll
  for (int q = 0; q < 4; ++q) vj[q] = pj[lane + 64 * q];

  float ssi = 0.f, ssj = 0.f, dot = 0.f;
#pragma unroll
  for (int q = 0; q < 4; ++q) {
    ssi += vi[q].x * vi[q].x + vi[q].y * vi[q].y + vi[q].z * vi[q].z + vi[q].w * vi[q].w;
    ssj += vj[q].x * vj[q].x + vj[q].y * vj[q].y + vj[q].z * vj[q].z + vj[q].w * vj[q].w;
    dot += vi[q].x * vj[q].x + vi[q].y * vj[q].y + vi[q].z * vj[q].z + vi[q].w * vj[q].w;
  }
#pragma unroll
  for (int o = 32; o; o >>= 1) {
    ssi += __shfl_xor(ssi, o, 64);
    ssj += __shfl_xor(ssj, o, 64);
    dot += __shfl_xor(dot, o, 64);
  }
  const float invi = 1.0f / fmaxf(sqrtf(ssi), 1e-12f);
  const float invj = 1.0f / fmaxf(sqrtf(ssj), 1e-12f);

  uint32_t* poi = reinterpret_cast<uint32_t*>(reps + (size_t)k * DIM);
  uint32_t* poj = reinterpret_cast<uint32_t*>(reps + (size_t)(k + NROWS) * DIM);
#pragma unroll
  for (int q = 0; q < 4; ++q) {
    int di = __builtin_amdgcn_cvt_pk_fp8_f32(vi[q].x * invi, vi[q].y * invi, 0, false);
    di     = __builtin_amdgcn_cvt_pk_fp8_f32(vi[q].z * invi, vi[q].w * invi, di, true);
    int dj = __builtin_amdgcn_cvt_pk_fp8_f32(vj[q].x * invj, vj[q].y * invj, 0, false);
    dj     = __builtin_amdgcn_cvt_pk_fp8_f32(vj[q].z * invj, vj[q].w * invj, dj, true);
    poi[lane + 64 * q] = (uint32_t)di;
    poj[lane + 64 * q] = (uint32_t)dj;
  }
  if (lane == 0) pos[k] = dot * invi * invj;   // positive-pair cosine, fp32
}

// ---- kernel 2: fused sim-GEMM (MX-fp8) + exp + row/col sums, upper tri -----
// C-tile 128x128 (R7's verified geometry), 256 threads = 4 waves (2x2),
// wave-tile 64x64 = 4x4 grid of 16x16x128 scaled MFMAs, BK=128,
// DOUBLE-BUFFERED with prefetch-after-barrier:
//   stage(buf0); for it: { barrier; stage(buf[it+1]); compute(buf[it]); }
// vs R10: LDS is 64+2 KB (not 100) -> 2 blocks/CU stay resident, so dbuf
// within-block overlap COEXISTS with cross-block overlap (R10's failure was
// 1 block/CU: DMA prefetch serialized behind frag ds_reads on the lone
// block's LDS pipe with nothing else to run).
// Verified (R6/R7): A-frag A[m=lane&15][k=quad*32+j]; 32B-slot XOR swizzle
// (key=row&3) conflict-free; C/D col=lane&15,row=quad*4+reg.
__global__ __launch_bounds__(256, 4) void simsum_kernel(
    const uint8_t* __restrict__ reps, float* __restrict__ denom,
    const float* __restrict__ pos, unsigned int* __restrict__ cnt,
    float* __restrict__ out) {
  __shared__ __align__(16) uint8_t lA[2][128 * 128];  // 32 KB
  __shared__ __align__(16) uint8_t lB[2][128 * 128];  // 32 KB
  __shared__ float dl[128];   // row-side partial sums
  __shared__ float cl[128];   // col-side partial sums
  __shared__ unsigned int is_last;

  const int t    = threadIdx.x;
  const int lane = t & 63;
  const int wave = t >> 6;
  const int wm   = wave >> 1;      // wave row 0..1
  const int wn   = wave & 1;       // wave col 0..1

  // triangular unranking: f(b) = b*(129-b)/2 tiles before block-row b
  const int idx = blockIdx.x;      // 0..2079
  int brow = (int)(64.5f - sqrtf(64.5f * 64.5f - 2.0f * (float)idx));
  if (brow > 63) brow = 63;
  if (brow < 0) brow = 0;
  while ((brow + 1) * (129 - (brow + 1)) / 2 <= idx) ++brow;
  while (brow * (129 - brow) / 2 > idx) --brow;
  const int bcol = brow + (idx - brow * (129 - brow) / 2);
  const bool offdiag = (brow != bcol);

  const uint8_t* gA = reps + (size_t)brow * 128 * DIM;
  const uint8_t* gB = reps + (size_t)bcol * 128 * DIM;

  // staging: thread t -> rows q*32 + rr (rr=t>>3), 16B half-slot s16=t&7.
  // 32B chunk c32 = (s16>>1)^(rr&3); src byte = c32*32 + (s16&1)*16.
  const int rr  = t >> 3;                                      // 0..31
  const int swz = ((((t >> 1) & 3) ^ (rr & 3)) << 5) | ((t & 1) << 4);

  floatx4 acc[4][4];
#pragma unroll
  for (int i = 0; i < 4; ++i)
#pragma unroll
    for (int j = 0; j < 4; ++j) acc[i][j] = floatx4{0.f, 0.f, 0.f, 0.f};

  const int mrow = lane & 15;        // fragment row select
  const int quad = lane >> 4;        // k block 0..3 (32 bytes each)
  const int soff = (quad ^ (mrow & 3)) << 5;   // 32B slot of this lane's chunk

  // prologue: stage k-chunk 0 into buffer 0
#pragma unroll
  for (int q = 0; q < 4; ++q) {
    gload16(gA + (size_t)(q * 32 + rr) * DIM + swz, &lA[0][q * 4096 + t * 16]);
    gload16(gB + (size_t)(q * 32 + rr) * DIM + swz, &lB[0][q * 4096 + t * 16]);
  }

#pragma unroll 1
  for (int it = 0; it < 8; ++it) {
    __syncthreads();   // drains buf[it&1] loads (issued one compute phase ago)

    if (it < 7) {      // prefetch next chunk into the other buffer
      const int k0 = (it + 1) * 128;
      const int nb = (it + 1) & 1;
#pragma unroll
      for (int q = 0; q < 4; ++q) {
        gload16(gA + (size_t)(q * 32 + rr) * DIM + k0 + swz, &lA[nb][q * 4096 + t * 16]);
        gload16(gB + (size_t)(q * 32 + rr) * DIM + k0 + swz, &lB[nb][q * 4096 + t * 16]);
      }
    }

    const uint8_t* bufA = lA[it & 1];
    const uint8_t* bufB = lB[it & 1];
    F8 fb[4];
#pragma unroll
    for (int nt = 0; nt < 4; ++nt) {
      const uint8_t* pb = bufB + (wn * 64 + nt * 16 + mrow) * 128 + soff;
      fb[nt].v4[0] = *reinterpret_cast<const intx4*>(pb);
      fb[nt].v4[1] = *reinterpret_cast<const intx4*>(pb + 16);
    }
#pragma unroll
    for (int mt = 0; mt < 4; ++mt) {
      F8 fa;
      const uint8_t* pa = bufA + (wm * 64 + mt * 16 + mrow) * 128 + soff;
      fa.v4[0] = *reinterpret_cast<const intx4*>(pa);
      fa.v4[1] = *reinterpret_cast<const intx4*>(pa + 16);
#pragma unroll
      for (int nt = 0; nt < 4; ++nt)
        acc[mt][nt] = __builtin_amdgcn_mfma_scale_f32_16x16x128_f8f6f4(
            fa.v8, fb[nt].v8, acc[mt][nt], 0, 0, 0, SCALE1, 0, SCALE1);
    }
  }

  if (t < 128) dl[t] = 0.f; else cl[t - 128] = 0.f;
  __syncthreads();

  // exp in-place: acc now holds e = exp(sim/T)
#pragma unroll
  for (int mt = 0; mt < 4; ++mt)
#pragma unroll
    for (int nt = 0; nt < 4; ++nt)
#pragma unroll
      for (int r = 0; r < 4; ++r)
        acc[mt][nt][r] = __expf(acc[mt][nt][r] * INV_T);

  // row-sums: C/D layout (16x16): col=lane&15, row=quad*4+r
#pragma unroll
  for (int mt = 0; mt < 4; ++mt) {
#pragma unroll
    for (int r = 0; r < 4; ++r) {
      float s = acc[mt][0][r] + acc[mt][1][r] + acc[mt][2][r] + acc[mt][3][r];
      s += __shfl_xor(s, 1, 64);
      s += __shfl_xor(s, 2, 64);
      s += __shfl_xor(s, 4, 64);
      s += __shfl_xor(s, 8, 64);
      if ((lane & 15) == 0)
        atomicAdd(&dl[wm * 64 + mt * 16 + quad * 4 + r], s);
    }
  }

  // col-sums (mirror rows), off-diag tiles only
  if (offdiag) {
#pragma unroll
    for (int nt = 0; nt < 4; ++nt) {
      float c = 0.f;
#pragma unroll
      for (int mt = 0; mt < 4; ++mt)
#pragma unroll
        for (int r = 0; r < 4; ++r) c += acc[mt][nt][r];
      c += __shfl_xor(c, 16, 64);
      c += __shfl_xor(c, 32, 64);
      if (quad == 0)
        atomicAdd(&cl[wn * 64 + nt * 16 + mrow], c);
    }
  }
  __syncthreads();
  if (t < 128) {
    atomicAdd(&denom[brow * 128 + t], dl[t]);
    if (offdiag) atomicAdd(&denom[bcol * 128 + t], cl[t]);
  }
  // __syncthreads drains vmcnt(0): this block's device-scope denom atomics
  // are complete at the coherence point before the counter bump below.
  __syncthreads();
  if (t == 0)
    is_last = (__hip_atomic_fetch_add(cnt, 1u, __ATOMIC_RELAXED,
                                      __HIP_MEMORY_SCOPE_AGENT) == NTILES - 1)
                  ? 1u : 0u;
  __syncthreads();
  if (is_last) {
    float v = 0.f;
#pragma unroll
    for (int i = 0; i < TWON / 256; ++i) {
      float d = __hip_atomic_load(&denom[i * 256 + t], __ATOMIC_RELAXED,
                                  __HIP_MEMORY_SCOPE_AGENT);
      v += __logf(d - EXP_DIAG);
    }
    float p = 0.f;
#pragma unroll
    for (int i = 0; i < NROWS / 256; ++i)
      p += pos[i * 256 + t];
    v -= 4.0f * p;
#pragma unroll
    for (int o = 32; o; o >>= 1) v += __shfl_down(v, o, 64);
    if ((t & 63) == 0) dl[t >> 6] = v;
    __syncthreads();
    if (t == 0)
      out[0] = (dl[0] + dl[1] + dl[2] + dl[3]) * (1.0f / 8192.0f);
  }
}

extern "C" void kernel_launch(void* const* d_in, const int* in_sizes, int n_in,
                              void* d_out, int out_size, void* d_ws, size_t ws_size,
                              hipStream_t stream) {
  const float* emb_i = (const float*)d_in[0];
  const float* emb_j = (const float*)d_in[1];
  float* out = (float*)d_out;

  uint8_t* reps = (uint8_t*)d_ws;                                  // 8.39 MB fp8
  float* denom  = (float*)((char*)d_ws + (size_t)TWON * DIM);      // 32 KB
  float* pos    = denom + TWON;                                    // 16 KB
  unsigned int* cnt = (unsigned int*)(pos + NROWS);

  normpos_kernel<<<1024, 256, 0, stream>>>(emb_i, emb_j, reps, denom, pos, cnt);
  simsum_kernel<<<NTILES, 256, 0, stream>>>(reps, denom, pos, cnt, out);
}

// Round 12
// 132.829 us; speedup vs baseline: 1.1790x; 1.1378x over previous
//
#include <hip/hip_runtime.h>
#include <cstdint>
#include <cstddef>

#define NROWS 4096
#define DIM   1024            // elements per row; also BYTES per fp8 row
#define TWON  8192
#define INV_T 2.0f
// exp(2.0) = exp(sim_rr / T) for the masked diagonal (rows are unit-norm)
#define EXP_DIAG 7.38905609893065f
#define NT2   1056            // # of 256x128 tiles covering the upper triangle
#define SCALE1 0x7F7F7F7F     // 4x E8M0 unity scales (127 -> 2^0)

typedef float floatx4 __attribute__((ext_vector_type(4)));
typedef int   intx4   __attribute__((ext_vector_type(4)));
typedef int   intx8   __attribute__((ext_vector_type(8)));

union F8 { intx8 v8; intx4 v4[2]; };

__device__ __forceinline__ void gload16(const uint8_t* g, uint8_t* l) {
  __builtin_amdgcn_global_load_lds(
      (const __attribute__((address_space(1))) void*)g,
      (__attribute__((address_space(3))) void*)l,
      16, 0, 0);
}

// -- kernel 1: normalize -> fp8 reps, fp32 pos dot, zero denom/cnt ------------
// Wave-per-pair, no barriers, loads issued up front, HW packed fp8 convert.
__global__ __launch_bounds__(256) void normpos_kernel(
    const float* __restrict__ emb_i, const float* __restrict__ emb_j,
    uint8_t* __restrict__ reps, float* __restrict__ denom,
    float* __restrict__ pos, unsigned int* __restrict__ cnt) {
  const int t    = threadIdx.x;
  const int lane = t & 63;
  const int wave = t >> 6;
  if (blockIdx.x < 32) denom[blockIdx.x * 256 + t] = 0.f;
  if (blockIdx.x == 32 && t == 0) *cnt = 0u;

  const int k = blockIdx.x * 4 + wave;        // 0..4095 (pair index)
  const float4* pi = reinterpret_cast<const float4*>(emb_i + (size_t)k * DIM);
  const float4* pj = reinterpret_cast<const float4*>(emb_j + (size_t)k * DIM);

  float4 vi[4], vj[4];
#pragma unroll
  for (int q = 0; q < 4; ++q) vi[q] = pi[lane + 64 * q];
#pragma unroll
  for (int q = 0; q < 4; ++q) vj[q] = pj[lane + 64 * q];

  float ssi = 0.f, ssj = 0.f, dot = 0.f;
#pragma unroll
  for (int q = 0; q < 4; ++q) {
    ssi += vi[q].x * vi[q].x + vi[q].y * vi[q].y + vi[q].z * vi[q].z + vi[q].w * vi[q].w;
    ssj += vj[q].x * vj[q].x + vj[q].y * vj[q].y + vj[q].z * vj[q].z + vj[q].w * vj[q].w;
    dot += vi[q].x * vj[q].x + vi[q].y * vj[q].y + vi[q].z * vj[q].z + vi[q].w * vj[q].w;
  }
#pragma unroll
  for (int o = 32; o; o >>= 1) {
    ssi += __shfl_xor(ssi, o, 64);
    ssj += __shfl_xor(ssj, o, 64);
    dot += __shfl_xor(dot, o, 64);
  }
  const float invi = 1.0f / fmaxf(sqrtf(ssi), 1e-12f);
  const float invj = 1.0f / fmaxf(sqrtf(ssj), 1e-12f);

  uint32_t* poi = reinterpret_cast<uint32_t*>(reps + (size_t)k * DIM);
  uint32_t* poj = reinterpret_cast<uint32_t*>(reps + (size_t)(k + NROWS) * DIM);
#pragma unroll
  for (int q = 0; q < 4; ++q) {
    int di = __builtin_amdgcn_cvt_pk_fp8_f32(vi[q].x * invi, vi[q].y * invi, 0, false);
    di     = __builtin_amdgcn_cvt_pk_fp8_f32(vi[q].z * invi, vi[q].w * invi, di, true);
    int dj = __builtin_amdgcn_cvt_pk_fp8_f32(vj[q].x * invj, vj[q].y * invj, 0, false);
    dj     = __builtin_amdgcn_cvt_pk_fp8_f32(vj[q].z * invj, vj[q].w * invj, dj, true);
    poi[lane + 64 * q] = (uint32_t)di;
    poj[lane + 64 * q] = (uint32_t)dj;
  }
  if (lane == 0) pos[k] = dot * invi * invj;   // positive-pair cosine, fp32
}

// ---- kernel 2: fused sim-GEMM (MX-fp8) + exp + row/col sums, upper tri -----
// R9 configuration — best measured (simsum 65.8us). C-tile 256x128,
// 512 threads = 8 waves (4x2), each wave 4x4 grid of 16x16x128 scaled MFMAs,
// BK=128 -> 8 staging iters, single-buffered (R10/R11: dbuf regresses in
// every geometry — LDS-pipe contention + occupancy loss exceed drain hiding).
// XCD-contiguous remap keeps each XCD's tile range triangular-contiguous.
// Verified (R6/R7): A-frag A[m=lane&15][k=quad*32+j]; 32B-slot XOR swizzle
// (key=row&3) conflict-free; C/D col=lane&15,row=quad*4+reg.
__global__ __launch_bounds__(512, 4) void simsum_kernel(
    const uint8_t* __restrict__ reps, float* __restrict__ denom,
    const float* __restrict__ pos, unsigned int* __restrict__ cnt,
    float* __restrict__ out) {
  __shared__ __align__(16) uint8_t lA[256 * 128];  // 32 KB
  __shared__ __align__(16) uint8_t lB[128 * 128];  // 16 KB
  __shared__ float dl[256];   // row-side partial sums
  __shared__ float cl[128];   // col-side partial sums
  __shared__ unsigned int is_last;

  const int t    = threadIdx.x;
  const int lane = t & 63;
  const int wave = t >> 6;         // 0..7
  const int wm   = wave >> 1;      // wave row 0..3 (64-row strip)
  const int wn   = wave & 1;       // wave col 0..1 (64-col strip)

  // XCD-contiguous tile id, then unrank: f(bm) = bm*(65-bm) tiles before bm
  const int ridx = ((blockIdx.x & 7) * 132) + (blockIdx.x >> 3);  // 0..1055
  int bm = (int)(32.5f - sqrtf(1056.25f - (float)ridx));
  if (bm < 0) bm = 0;
  if (bm > 31) bm = 31;
  while (bm < 31 && (bm + 1) * (65 - (bm + 1)) <= ridx) ++bm;
  while (bm > 0 && bm * (65 - bm) > ridx) --bm;
  const int bn = 2 * bm + (ridx - bm * (65 - bm));   // 2bm..63

  const uint8_t* gA = reps + (size_t)bm * 256 * DIM;
  const uint8_t* gB = reps + (size_t)bn * 128 * DIM;

  // staging: thread t -> row q*64 + rr (rr=t>>3), 16B half-slot s16=t&7.
  // 32B chunk c32 = (s16>>1)^(rr&3); src byte = c32*32 + (s16&1)*16.
  const int rr  = t >> 3;                                      // 0..63
  const int swz = ((((t >> 1) & 3) ^ (rr & 3)) << 5) | ((t & 1) << 4);

  floatx4 acc[4][4];
#pragma unroll
  for (int i = 0; i < 4; ++i)
#pragma unroll
    for (int j = 0; j < 4; ++j) acc[i][j] = floatx4{0.f, 0.f, 0.f, 0.f};

  const int mrow = lane & 15;        // fragment row select
  const int quad = lane >> 4;        // k block 0..3 (32 bytes each)
  const int soff = (quad ^ (mrow & 3)) << 5;   // 32B slot of this lane's chunk

#pragma unroll 1
  for (int k0 = 0; k0 < DIM; k0 += 128) {
    __syncthreads();
#pragma unroll
    for (int q = 0; q < 4; ++q)   // A: 256 rows
      gload16(gA + (size_t)(q * 64 + rr) * DIM + k0 + swz, lA + q * 8192 + t * 16);
#pragma unroll
    for (int q = 0; q < 2; ++q)   // B: 128 rows
      gload16(gB + (size_t)(q * 64 + rr) * DIM + k0 + swz, lB + q * 8192 + t * 16);
    __syncthreads();   // compiler inserts vmcnt(0) drain here

    F8 fb[4];
#pragma unroll
    for (int nt = 0; nt < 4; ++nt) {
      const uint8_t* pb = lB + (wn * 64 + nt * 16 + mrow) * 128 + soff;
      fb[nt].v4[0] = *reinterpret_cast<const intx4*>(pb);
      fb[nt].v4[1] = *reinterpret_cast<const intx4*>(pb + 16);
    }
#pragma unroll
    for (int mt = 0; mt < 4; ++mt) {
      F8 fa;
      const uint8_t* pa = lA + (wm * 64 + mt * 16 + mrow) * 128 + soff;
      fa.v4[0] = *reinterpret_cast<const intx4*>(pa);
      fa.v4[1] = *reinterpret_cast<const intx4*>(pa + 16);
#pragma unroll
      for (int nt = 0; nt < 4; ++nt)
        acc[mt][nt] = __builtin_amdgcn_mfma_scale_f32_16x16x128_f8f6f4(
            fa.v8, fb[nt].v8, acc[mt][nt], 0, 0, 0, SCALE1, 0, SCALE1);
    }
  }

  if (t < 256) dl[t] = 0.f;
  else if (t < 384) cl[t - 256] = 0.f;
  __syncthreads();

  // half-tile masks (wave-uniform): h = which 128-row half this wave is in
  const int  h       = wm >> 1;
  const int  r128    = 2 * bm + h;
  const bool skipAll = (r128 > bn);    // below-diagonal half (bn==2bm, h==1)
  const bool doCol   = (r128 < bn);    // strictly-above-diagonal half

  // exp in-place: acc now holds e = exp(sim/T)
#pragma unroll
  for (int mt = 0; mt < 4; ++mt)
#pragma unroll
    for (int nt = 0; nt < 4; ++nt)
#pragma unroll
      for (int r = 0; r < 4; ++r)
        acc[mt][nt][r] = __expf(acc[mt][nt][r] * INV_T);

  // row-sums: C/D layout (16x16): col=lane&15, row=quad*4+r
  if (!skipAll) {
#pragma unroll
    for (int mt = 0; mt < 4; ++mt) {
#pragma unroll
      for (int r = 0; r < 4; ++r) {
        float s = acc[mt][0][r] + acc[mt][1][r] + acc[mt][2][r] + acc[mt][3][r];
        s += __shfl_xor(s, 1, 64);
        s += __shfl_xor(s, 2, 64);
        s += __shfl_xor(s, 4, 64);
        s += __shfl_xor(s, 8, 64);
        if ((lane & 15) == 0)
          atomicAdd(&dl[wm * 64 + mt * 16 + quad * 4 + r], s);
      }
    }
  }

  // col-sums (mirror rows), strictly-off-diagonal halves only
  if (doCol) {
#pragma unroll
    for (int nt = 0; nt < 4; ++nt) {
      float c = 0.f;
#pragma unroll
      for (int mt = 0; mt < 4; ++mt)
#pragma unroll
        for (int r = 0; r < 4; ++r) c += acc[mt][nt][r];
      c += __shfl_xor(c, 16, 64);
      c += __shfl_xor(c, 32, 64);
      if (quad == 0)
        atomicAdd(&cl[wn * 64 + nt * 16 + mrow], c);
    }
  }
  __syncthreads();
  if (t < 256) {
    const bool rowOk = !((bn == 2 * bm) && (t >= 128));
    if (rowOk) atomicAdd(&denom[bm * 256 + t], dl[t]);
  } else if (t < 384 && bn > 2 * bm) {
    atomicAdd(&denom[bn * 128 + (t - 256)], cl[t - 256]);
  }
  // __syncthreads drains vmcnt(0): this block's device-scope denom atomics
  // are complete at the coherence point before the counter bump below.
  __syncthreads();
  if (t == 0)
    is_last = (__hip_atomic_fetch_add(cnt, 1u, __ATOMIC_RELAXED,
                                      __HIP_MEMORY_SCOPE_AGENT) == NT2 - 1)
                  ? 1u : 0u;
  __syncthreads();
  if (is_last) {
    float v = 0.f;
#pragma unroll
    for (int i = 0; i < TWON / 512; ++i) {
      float d = __hip_atomic_load(&denom[i * 512 + t], __ATOMIC_RELAXED,
                                  __HIP_MEMORY_SCOPE_AGENT);
      v += __logf(d - EXP_DIAG);
    }
    float p = 0.f;
#pragma unroll
    for (int i = 0; i < NROWS / 512; ++i)
      p += pos[i * 512 + t];
    v -= 4.0f * p;
#pragma unroll
    for (int o = 32; o; o >>= 1) v += __shfl_down(v, o, 64);
    if ((t & 63) == 0) dl[t >> 6] = v;
    __syncthreads();
    if (t == 0) {
      float tot = 0.f;
#pragma unroll
      for (int w = 0; w < 8; ++w) tot += dl[w];
      out[0] = tot * (1.0f / 8192.0f);
    }
  }
}

extern "C" void kernel_launch(void* const* d_in, const int* in_sizes, int n_in,
                              void* d_out, int out_size, void* d_ws, size_t ws_size,
                              hipStream_t stream) {
  const float* emb_i = (const float*)d_in[0];
  const float* emb_j = (const float*)d_in[1];
  float* out = (float*)d_out;

  uint8_t* reps = (uint8_t*)d_ws;                                  // 8.39 MB fp8
  float* denom  = (float*)((char*)d_ws + (size_t)TWON * DIM);      // 32 KB
  float* pos    = denom + TWON;                                    // 16 KB
  unsigned int* cnt = (unsigned int*)(pos + NROWS);

  normpos_kernel<<<1024, 256, 0, stream>>>(emb_i, emb_j, reps, denom, pos, cnt);
  simsum_kernel<<<NT2, 512, 0, stream>>>(reps, denom, pos, cnt, out);
}